// Round 8
// baseline (330.111 us; speedup 1.0000x reference)
//
#include <hip/hip_runtime.h>
#include <hip/hip_bf16.h>

// GCNEncoder: 2-layer GCN, out-degree norm. N=100000, E=1600000, 128->128->64, fp32 I/O.
// R8: (1) agg128 XCD-column-split (blockIdx%8 round-robin heuristic; each XCD touches one
// 128B line per row -> per-XCD compulsory fills halve); (2) int4 idx load + 1-iter prefetch
// in both aggregates (CSR segments padded to 4-edge alignment for 16B loads); (3) GEMM reads
// B-fragments from preconverted bf16 W[n][k] in global (L1-resident) -> LDS 52->17KB, 8 blk/CU.

typedef __attribute__((ext_vector_type(8))) short short8;
typedef __attribute__((ext_vector_type(4))) float floatx4;

__device__ inline unsigned short f2bf(float f) {
    union { float f; unsigned u; } v; v.f = f;
    unsigned r = v.u + 0x7FFF + ((v.u >> 16) & 1);  // RNE
    return (unsigned short)(r >> 16);
}
__device__ inline float bf2f(unsigned b) {
    union { unsigned u; float f; } v; v.u = b << 16;
    return v.f;
}
__device__ inline float bf2f_hi(unsigned b) {
    union { unsigned u; float f; } v; v.u = b & 0xFFFF0000u;
    return v.f;
}

#define NBMAX 512   // max 256-node buckets -> N <= 131072 (src < 2^24 for packing)
#define CAP   8192  // fixed bucket capacity; mean 4092 + <=768 alignment pad -> safe

// ---- W preconvert: fp32 [k][n] -> bf16 [n][k] (both layers in one launch) ----
__global__ __launch_bounds__(256) void convw_kernel(
    const float* __restrict__ W1, const float* __restrict__ W2,
    unsigned short* __restrict__ Wb1, unsigned short* __restrict__ Wb2)
{
    int i = blockIdx.x * 256 + threadIdx.x;
    if (i < 128 * 128) {
        int k = i >> 7, n = i & 127;
        Wb1[n * 128 + k] = f2bf(__builtin_bit_cast(unsigned, W1[k * 128 + n]) ? W1[k * 128 + n] : 0.0f);
    }
    i -= 128 * 128;
    if (i >= 0 && i < 128 * 64) {
        int k = i >> 6, n = i & 63;
        Wb2[n * 128 + k] = f2bf(W2[k * 64 + n]);
    }
}

// ---- pass 1: LDS bucket histograms -> reserve runs via global cursors -> scatter ----
__global__ __launch_bounds__(256) void scatter2_kernel(
    const int* __restrict__ src, const int* __restrict__ dst, int E,
    int* __restrict__ cnt_d, int* __restrict__ cnt_s,   // stride-16 padded cursors
    unsigned* __restrict__ pairs, unsigned char* __restrict__ srcs_b, int NB)
{
    __shared__ int hd[NBMAX], bd[NBMAX], cd_[NBMAX];
    __shared__ int hs[NBMAX], bs[NBMAX], cs_[NBMAX];
    for (int i = threadIdx.x; i < NB; i += 256) { hd[i] = 0; cd_[i] = 0; hs[i] = 0; cs_[i] = 0; }
    __syncthreads();
    const int e0 = blockIdx.x * 8192;
    const int e1 = min(e0 + 8192, E);
    for (int i = e0 + threadIdx.x; i < e1; i += 256) {
        atomicAdd(&hd[dst[i] >> 8], 1);
        atomicAdd(&hs[src[i] >> 8], 1);
    }
    __syncthreads();
    for (int i = threadIdx.x; i < NB; i += 256) {
        if (hd[i]) bd[i] = atomicAdd(&cnt_d[i * 16], hd[i]);
        if (hs[i]) bs[i] = atomicAdd(&cnt_s[i * 16], hs[i]);
    }
    __syncthreads();
    for (int i = e0 + threadIdx.x; i < e1; i += 256) {
        int sv = src[i], dv = dst[i];
        int b = dv >> 8;
        int slot = atomicAdd(&cd_[b], 1);
        pairs[(size_t)b * CAP + bd[b] + slot] = ((unsigned)(dv & 255) << 24) | (unsigned)sv;
        int b2 = sv >> 8;
        int slot2 = atomicAdd(&cs_[b2], 1);
        srcs_b[(size_t)b2 * CAP + bs[b2] + slot2] = (unsigned char)(sv & 255);
    }
}

// ---- pass 2 (fused): per-bucket dst sort (4-aligned segment starts) -> sorted_src +
//      (start,end) per node; src hist -> deg_inv ----
__global__ __launch_bounds__(256) void bucket_finalize_kernel(
    const unsigned* __restrict__ pairs, const unsigned char* __restrict__ srcs_b,
    const int* __restrict__ cnt_d, const int* __restrict__ cnt_s,
    int* __restrict__ sorted_src, int2* __restrict__ se,
    float* __restrict__ deg_inv, int N)
{
    const int b = blockIdx.x;
    const int node0 = b << 8;
    const int t = threadIdx.x;
    const size_t base = (size_t)b * CAP;
    __shared__ int hist[256];
    __shared__ int cur[256];
    __shared__ int pre[256];

    const int cd = cnt_d[b * 16];
    hist[t] = 0;
    __syncthreads();
    for (int i = t; i < cd; i += 256)
        atomicAdd(&hist[pairs[base + i] >> 24], 1);
    __syncthreads();
    int v = hist[t];
    int v4 = (v + 3) & ~3;  // pad each node's segment to 4-edge alignment (16B int4 loads)
    pre[t] = v4;
    __syncthreads();
    for (int o = 1; o < 256; o <<= 1) {
        int add = (t >= o) ? pre[t - o] : 0;
        __syncthreads();
        pre[t] += add;
        __syncthreads();
    }
    int excl = pre[t] - v4;
    cur[t] = excl;
    if (node0 + t < N)
        se[node0 + t] = make_int2((int)base + excl, (int)base + excl + v);
    __syncthreads();
    for (int i = t; i < cd; i += 256) {
        unsigned p = pairs[base + i];
        int pos = atomicAdd(&cur[p >> 24], 1);
        sorted_src[base + pos] = (int)(p & 0xFFFFFFu);
    }

    __syncthreads();
    hist[t] = 0;
    __syncthreads();
    const int cs = cnt_s[b * 16];
    for (int i = t; i < cs; i += 256)
        atomicAdd(&hist[srcs_b[base + i]], 1);
    __syncthreads();
    if (node0 + t < N) {
        int d = hist[t];
        deg_inv[node0 + t] = 1.0f / (float)(d < 1 ? 1 : d);
    }
}

// ---------------- MFMA GEMM, 64-row M-tile, B from global bf16 [n][k] ----------------
// AF=1: A fp32 scaled by deg_inv[row] (layer 1). AF=0: A bf16 already scaled (layer 2).
template <int NC, int AF>
__global__ __launch_bounds__(256) void gemm_mfma_kernel(
    const void* __restrict__ Ap, const unsigned short* __restrict__ Wb,
    const float* __restrict__ scale, unsigned short* __restrict__ Cb, int M)
{
    __shared__ unsigned short Al[64][136];   // 17.4 KB only

    const int t = threadIdx.x;
    const int r0 = blockIdx.x * 64;

    for (int idx = t; idx < 64 * 32; idx += 256) {
        int r = idx >> 5, c4 = (idx & 31) << 2;
        int rg = r0 + r;
        ushort4 w;
        if (rg < M) {
            if (AF) {
                float s = scale[rg];
                float4 v = *(const float4*)&((const float*)Ap)[(size_t)rg * 128 + c4];
                w.x = f2bf(v.x * s); w.y = f2bf(v.y * s);
                w.z = f2bf(v.z * s); w.w = f2bf(v.w * s);
            } else {
                w = *(const ushort4*)&((const unsigned short*)Ap)[(size_t)rg * 128 + c4];
            }
        } else {
            w.x = w.y = w.z = w.w = 0;
        }
        *(ushort4*)&Al[r][c4] = w;
    }
    __syncthreads();

    constexpr int NT = NC / 16;
    const int wm = t >> 6;
    const int lane = t & 63;
    const int lm = lane & 15;
    const int lk = (lane >> 4) * 8;

    floatx4 acc[NT];
#pragma unroll
    for (int j = 0; j < NT; ++j) acc[j] = (floatx4){0.f, 0.f, 0.f, 0.f};

#pragma unroll
    for (int kk = 0; kk < 4; ++kk) {
        const int kb = kk * 32 + lk;
        short8 af = *(const short8*)&Al[wm * 16 + lm][kb];
#pragma unroll
        for (int j = 0; j < NT; ++j) {
            short8 bfr = *(const short8*)&Wb[(size_t)(j * 16 + lm) * 128 + kb];
            acc[j] = __builtin_amdgcn_mfma_f32_16x16x32_bf16(af, bfr, acc[j], 0, 0, 0);
        }
    }

    const int rbase = r0 + wm * 16 + (lane >> 4) * 4;
#pragma unroll
    for (int reg = 0; reg < 4; ++reg) {
        int rg = rbase + reg;
        if (rg < M) {
#pragma unroll
            for (int j = 0; j < NT; ++j)
                Cb[(size_t)rg * NC + j * 16 + lm] = f2bf(acc[j][reg]);
        }
    }
}

// ---------------- aggregate C=128: XCD column-split, half-wave/node, int4 idx prefetch ----------------
// blockIdx%8 ~ XCD (round-robin heuristic). cg=(blk>>2)&1 picks 64-col half (one 128B line).
// u=(blk>>3)*4+(blk&3): each (u,cg) pair hit exactly once. Epilogue: relu(.+b1)*deg_inv -> bf16.
__global__ __launch_bounds__(256) void aggregate128_kernel(
    const int2* __restrict__ se, const int* __restrict__ sorted_src,
    const unsigned* __restrict__ val, const float* __restrict__ bias,
    const float* __restrict__ deg_inv, unsigned* __restrict__ outb, int N)
{
    const int blk = blockIdx.x;
    const int u = (blk >> 3) * 4 + (blk & 3);
    const int cg = (blk >> 2) & 1;
    const int node = u * 8 + (threadIdx.x >> 5);
    if (node >= N) return;
    const int l = threadIdx.x & 31;
    const int cbase = cg * 32 + l;  // dword column (row = 64 dwords)
    int2 r = se[node];
    int e = r.x;
    const int end = r.y;
    float a0 = 0.f, a1 = 0.f;
    if (e + 4 <= end) {
        int4 idx = *(const int4*)&sorted_src[e];
        for (; e + 8 <= end; e += 4) {
            int4 nidx = *(const int4*)&sorted_src[e + 4];
            unsigned v0 = val[(size_t)idx.x * 64 + cbase];
            unsigned v1 = val[(size_t)idx.y * 64 + cbase];
            unsigned v2 = val[(size_t)idx.z * 64 + cbase];
            unsigned v3 = val[(size_t)idx.w * 64 + cbase];
            a0 += (bf2f(v0 & 0xFFFF) + bf2f(v1 & 0xFFFF)) + (bf2f(v2 & 0xFFFF) + bf2f(v3 & 0xFFFF));
            a1 += (bf2f_hi(v0) + bf2f_hi(v1)) + (bf2f_hi(v2) + bf2f_hi(v3));
            idx = nidx;
        }
        unsigned v0 = val[(size_t)idx.x * 64 + cbase];
        unsigned v1 = val[(size_t)idx.y * 64 + cbase];
        unsigned v2 = val[(size_t)idx.z * 64 + cbase];
        unsigned v3 = val[(size_t)idx.w * 64 + cbase];
        a0 += (bf2f(v0 & 0xFFFF) + bf2f(v1 & 0xFFFF)) + (bf2f(v2 & 0xFFFF) + bf2f(v3 & 0xFFFF));
        a1 += (bf2f_hi(v0) + bf2f_hi(v1)) + (bf2f_hi(v2) + bf2f_hi(v3));
        e += 4;
    }
    for (; e < end; ++e) {
        unsigned v = val[(size_t)sorted_src[e] * 64 + cbase];
        a0 += bf2f(v & 0xFFFF);
        a1 += bf2f_hi(v);
    }
    float di = deg_inv[node];
    float2 bv = *(const float2*)&bias[cg * 64 + 2 * l];
    a0 = fmaxf(a0 + bv.x, 0.f) * di;
    a1 = fmaxf(a1 + bv.y, 0.f) * di;
    outb[(size_t)node * 64 + cbase] = (unsigned)f2bf(a0) | ((unsigned)f2bf(a1) << 16);
}

// ---------------- aggregate C=64 (bf16 in, fp32 out, +bias): half-wave/node, int4 prefetch ----------------
__global__ __launch_bounds__(256) void aggregate64_kernel(
    const int2* __restrict__ se, const int* __restrict__ sorted_src,
    const unsigned* __restrict__ val, const float* __restrict__ bias,
    float* __restrict__ out, int N)
{
    int node = blockIdx.x * 8 + (threadIdx.x >> 5);
    if (node >= N) return;
    int l = threadIdx.x & 31;
    int2 r = se[node];
    int e = r.x;
    const int end = r.y;
    float ax = 0.f, ay = 0.f;
    if (e + 4 <= end) {
        int4 idx = *(const int4*)&sorted_src[e];
        for (; e + 8 <= end; e += 4) {
            int4 nidx = *(const int4*)&sorted_src[e + 4];
            unsigned v0 = val[(size_t)idx.x * 32 + l];
            unsigned v1 = val[(size_t)idx.y * 32 + l];
            unsigned v2 = val[(size_t)idx.z * 32 + l];
            unsigned v3 = val[(size_t)idx.w * 32 + l];
            ax += (bf2f(v0 & 0xFFFF) + bf2f(v1 & 0xFFFF)) + (bf2f(v2 & 0xFFFF) + bf2f(v3 & 0xFFFF));
            ay += (bf2f_hi(v0) + bf2f_hi(v1)) + (bf2f_hi(v2) + bf2f_hi(v3));
            idx = nidx;
        }
        unsigned v0 = val[(size_t)idx.x * 32 + l];
        unsigned v1 = val[(size_t)idx.y * 32 + l];
        unsigned v2 = val[(size_t)idx.z * 32 + l];
        unsigned v3 = val[(size_t)idx.w * 32 + l];
        ax += (bf2f(v0 & 0xFFFF) + bf2f(v1 & 0xFFFF)) + (bf2f(v2 & 0xFFFF) + bf2f(v3 & 0xFFFF));
        ay += (bf2f_hi(v0) + bf2f_hi(v1)) + (bf2f_hi(v2) + bf2f_hi(v3));
        e += 4;
    }
    for (; e < end; ++e) {
        unsigned v = val[(size_t)sorted_src[e] * 32 + l];
        ax += bf2f(v & 0xFFFF);
        ay += bf2f_hi(v);
    }
    float2 o = make_float2(ax + bias[2 * l], ay + bias[2 * l + 1]);
    *(float2*)&out[(size_t)node * 64 + 2 * l] = o;
}

extern "C" void kernel_launch(void* const* d_in, const int* in_sizes, int n_in,
                              void* d_out, int out_size, void* d_ws, size_t ws_size,
                              hipStream_t stream) {
    const float* x  = (const float*)d_in[0];
    const int*   ei = (const int*)d_in[1];
    const float* W1 = (const float*)d_in[2];
    const float* b1 = (const float*)d_in[3];
    const float* W2 = (const float*)d_in[4];
    const float* b2 = (const float*)d_in[5];
    float* out = (float*)d_out;

    const int N = in_sizes[0] / 128;
    const int E = in_sizes[1] / 2;
    const int* src = ei;
    const int* dst = ei + E;
    const int NB = (N + 255) >> 8;

    char* ws = (char*)d_ws;
    size_t off = 0;
    auto alloc = [&](size_t bytes) {
        void* p = ws + off;
        off = (off + bytes + 255) & ~(size_t)255;
        return p;
    };
    float* deg_inv  = (float*)alloc((size_t)N * 4);
    int2*  se       = (int2*)alloc((size_t)N * 8);
    int*   cnt_d    = (int*)alloc((size_t)NBMAX * 16 * 4 * 2);  // cnt_d | cnt_s adjacent
    int*   cnt_s    = cnt_d + (size_t)NBMAX * 16;
    unsigned short* Wb1 = (unsigned short*)alloc((size_t)128 * 128 * 2);
    unsigned short* Wb2 = (unsigned short*)alloc((size_t)64 * 128 * 2);
    unsigned*      pairs  = (unsigned*)alloc((size_t)NBMAX * CAP * 4);
    unsigned char* srcs_b = (unsigned char*)alloc((size_t)NBMAX * CAP);
    int*   sorted_src = (int*)alloc((size_t)NBMAX * CAP * 4);
    unsigned short* h    = (unsigned short*)alloc((size_t)N * 128 * 2);
    unsigned short* out1 = (unsigned short*)alloc((size_t)N * 128 * 2);
    unsigned short* g    = h;  // h dead after aggregate1

    hipMemsetAsync(cnt_d, 0, (size_t)NBMAX * 16 * 4 * 2, stream);

    convw_kernel<<<96, 256, 0, stream>>>(W1, W2, Wb1, Wb2);
    scatter2_kernel<<<(E + 8191) / 8192, 256, 0, stream>>>(src, dst, E, cnt_d, cnt_s,
                                                           pairs, srcs_b, NB);
    bucket_finalize_kernel<<<NB, 256, 0, stream>>>(pairs, srcs_b, cnt_d, cnt_s,
                                                   sorted_src, se, deg_inv, N);

    const int gblocks = (N + 63) / 64;
    // layer 1: h = bf16((x*di) @ W1); out1 = bf16(relu(Agg(h)+b1) * di)
    gemm_mfma_kernel<128, 1><<<gblocks, 256, 0, stream>>>(x, Wb1, deg_inv, h, N);
    {
        const int G = (N + 7) / 8;          // node groups of 8
        const int blocks = ((G + 3) / 4) * 8;  // (u,cg) cover: u=(b>>3)*4+(b&3), cg=(b>>2)&1
        aggregate128_kernel<<<blocks, 256, 0, stream>>>(se, sorted_src, (const unsigned*)h, b1,
                                                        deg_inv, (unsigned*)out1, N);
    }
    // layer 2: g = bf16(out1 @ W2); out = Agg(g) + b2
    gemm_mfma_kernel<64, 0><<<gblocks, 256, 0, stream>>>(out1, Wb2, deg_inv, g, N);
    aggregate64_kernel<<<(N + 7) / 8, 256, 0, stream>>>(se, sorted_src, (const unsigned*)g, b2, out, N);
}

// Round 9
// 309.804 us; speedup vs baseline: 1.0655x; 1.0655x over previous
//
#include <hip/hip_runtime.h>
#include <hip/hip_bf16.h>

// GCNEncoder: 2-layer GCN, out-degree norm. N=100000, E=1600000, 128->128->64, fp32 I/O.
// R9: revert R8's agg128 column split (FETCH only -12% vs predicted -50%; VALU 32->46% from
// halved load width — net +7.4us). Keep int4 idx prefetch + 4-aligned CSR segments.
// New: GEMMs with NO LDS — A fragments loaded per-lane directly from global (m=lane&15 rows,
// wave covers one 128B line per (row,kk)), fp32->bf16 convert in reg, B from bf16 Wb[n][k]
// (L1-resident), deg_inv commuted to epilogue. No barrier, no staging; occupancy VGPR-bound.
// Cursor zeroing folded into convw (one fewer dispatch).

typedef __attribute__((ext_vector_type(8))) short short8;
typedef __attribute__((ext_vector_type(4))) float floatx4;

__device__ inline unsigned short f2bf(float f) {
    union { float f; unsigned u; } v; v.f = f;
    unsigned r = v.u + 0x7FFF + ((v.u >> 16) & 1);  // RNE
    return (unsigned short)(r >> 16);
}
__device__ inline float bf2f(unsigned b) {
    union { unsigned u; float f; } v; v.u = b << 16;
    return v.f;
}
__device__ inline float bf2f_hi(unsigned b) {
    union { unsigned u; float f; } v; v.u = b & 0xFFFF0000u;
    return v.f;
}

#define NBMAX 512   // max 256-node buckets -> N <= 131072 (src < 2^24 for packing)
#define CAP   8192  // fixed bucket capacity; mean 4092 + <=768 alignment pad -> safe

// ---- W preconvert fp32[k][n] -> bf16[n][k] for both layers; also zeros bucket cursors ----
__global__ __launch_bounds__(256) void convw_kernel(
    const float* __restrict__ W1, const float* __restrict__ W2,
    unsigned short* __restrict__ Wb1, unsigned short* __restrict__ Wb2,
    int* __restrict__ cnt)
{
    int i = blockIdx.x * 256 + threadIdx.x;
    if (i < NBMAX * 32) cnt[i] = 0;  // cnt_d | cnt_s (2 * NBMAX * 16 ints)
    if (i < 128 * 128) {
        int k = i >> 7, n = i & 127;
        Wb1[n * 128 + k] = f2bf(W1[k * 128 + n]);
    }
    i -= 128 * 128;
    if (i >= 0 && i < 128 * 64) {
        int k = i >> 6, n = i & 63;
        Wb2[n * 128 + k] = f2bf(W2[k * 64 + n]);
    }
}

// ---- pass 1: LDS bucket histograms -> reserve runs via global cursors -> scatter ----
__global__ __launch_bounds__(256) void scatter2_kernel(
    const int* __restrict__ src, const int* __restrict__ dst, int E,
    int* __restrict__ cnt_d, int* __restrict__ cnt_s,   // stride-16 padded cursors
    unsigned* __restrict__ pairs, unsigned char* __restrict__ srcs_b, int NB)
{
    __shared__ int hd[NBMAX], bd[NBMAX], cd_[NBMAX];
    __shared__ int hs[NBMAX], bs[NBMAX], cs_[NBMAX];
    for (int i = threadIdx.x; i < NB; i += 256) { hd[i] = 0; cd_[i] = 0; hs[i] = 0; cs_[i] = 0; }
    __syncthreads();
    const int e0 = blockIdx.x * 8192;
    const int e1 = min(e0 + 8192, E);
    for (int i = e0 + threadIdx.x; i < e1; i += 256) {
        atomicAdd(&hd[dst[i] >> 8], 1);
        atomicAdd(&hs[src[i] >> 8], 1);
    }
    __syncthreads();
    for (int i = threadIdx.x; i < NB; i += 256) {
        if (hd[i]) bd[i] = atomicAdd(&cnt_d[i * 16], hd[i]);
        if (hs[i]) bs[i] = atomicAdd(&cnt_s[i * 16], hs[i]);
    }
    __syncthreads();
    for (int i = e0 + threadIdx.x; i < e1; i += 256) {
        int sv = src[i], dv = dst[i];
        int b = dv >> 8;
        int slot = atomicAdd(&cd_[b], 1);
        pairs[(size_t)b * CAP + bd[b] + slot] = ((unsigned)(dv & 255) << 24) | (unsigned)sv;
        int b2 = sv >> 8;
        int slot2 = atomicAdd(&cs_[b2], 1);
        srcs_b[(size_t)b2 * CAP + bs[b2] + slot2] = (unsigned char)(sv & 255);
    }
}

// ---- pass 2 (fused): per-bucket dst sort (4-aligned segment starts) -> sorted_src +
//      (start,end) per node; src hist -> deg_inv ----
__global__ __launch_bounds__(256) void bucket_finalize_kernel(
    const unsigned* __restrict__ pairs, const unsigned char* __restrict__ srcs_b,
    const int* __restrict__ cnt_d, const int* __restrict__ cnt_s,
    int* __restrict__ sorted_src, int2* __restrict__ se,
    float* __restrict__ deg_inv, int N)
{
    const int b = blockIdx.x;
    const int node0 = b << 8;
    const int t = threadIdx.x;
    const size_t base = (size_t)b * CAP;
    __shared__ int hist[256];
    __shared__ int cur[256];
    __shared__ int pre[256];

    const int cd = cnt_d[b * 16];
    hist[t] = 0;
    __syncthreads();
    for (int i = t; i < cd; i += 256)
        atomicAdd(&hist[pairs[base + i] >> 24], 1);
    __syncthreads();
    int v = hist[t];
    int v4 = (v + 3) & ~3;  // 4-edge aligned segments (16B int4 idx loads)
    pre[t] = v4;
    __syncthreads();
    for (int o = 1; o < 256; o <<= 1) {
        int add = (t >= o) ? pre[t - o] : 0;
        __syncthreads();
        pre[t] += add;
        __syncthreads();
    }
    int excl = pre[t] - v4;
    cur[t] = excl;
    if (node0 + t < N)
        se[node0 + t] = make_int2((int)base + excl, (int)base + excl + v);
    __syncthreads();
    for (int i = t; i < cd; i += 256) {
        unsigned p = pairs[base + i];
        int pos = atomicAdd(&cur[p >> 24], 1);
        sorted_src[base + pos] = (int)(p & 0xFFFFFFu);
    }

    __syncthreads();
    hist[t] = 0;
    __syncthreads();
    const int cs = cnt_s[b * 16];
    for (int i = t; i < cs; i += 256)
        atomicAdd(&hist[srcs_b[base + i]], 1);
    __syncthreads();
    if (node0 + t < N) {
        int d = hist[t];
        deg_inv[node0 + t] = 1.0f / (float)(d < 1 ? 1 : d);
    }
}

// ---------------- MFMA GEMM, no LDS: per-lane A fragments straight from global ----------------
// 64 rows/block (4 waves x 16 rows). AF=1: A fp32, scale (deg_inv) applied in epilogue.
// AF=0: A bf16 already scaled. B = bf16 Wb[n][k], L1/L2-resident.
template <int NC, int AF>
__global__ __launch_bounds__(256) void gemm_mfma_kernel(
    const void* __restrict__ Ap, const unsigned short* __restrict__ Wb,
    const float* __restrict__ scale, unsigned short* __restrict__ Cb, int M)
{
    constexpr int NT = NC / 16;
    const int t = threadIdx.x;
    const int wm = t >> 6;
    const int lane = t & 63;
    const int lm = lane & 15;
    const int lk = (lane >> 4) * 8;

    const int r0 = blockIdx.x * 64 + wm * 16;
    int row = r0 + lm;
    if (row >= M) row = M - 1;  // clamp loads; stores are guarded

    floatx4 acc[NT];
#pragma unroll
    for (int j = 0; j < NT; ++j) acc[j] = (floatx4){0.f, 0.f, 0.f, 0.f};

#pragma unroll
    for (int kk = 0; kk < 4; ++kk) {
        const int kb = kk * 32 + lk;
        short8 af;
        if (AF) {
            const float* arow = (const float*)Ap + (size_t)row * 128 + kb;
            float4 a0 = *(const float4*)arow;
            float4 a1 = *(const float4*)(arow + 4);
            af[0] = (short)f2bf(a0.x); af[1] = (short)f2bf(a0.y);
            af[2] = (short)f2bf(a0.z); af[3] = (short)f2bf(a0.w);
            af[4] = (short)f2bf(a1.x); af[5] = (short)f2bf(a1.y);
            af[6] = (short)f2bf(a1.z); af[7] = (short)f2bf(a1.w);
        } else {
            af = *(const short8*)&((const unsigned short*)Ap)[(size_t)row * 128 + kb];
        }
#pragma unroll
        for (int j = 0; j < NT; ++j) {
            short8 bfr = *(const short8*)&Wb[(size_t)(j * 16 + lm) * 128 + kb];
            acc[j] = __builtin_amdgcn_mfma_f32_16x16x32_bf16(af, bfr, acc[j], 0, 0, 0);
        }
    }

    const int rbase = r0 + (lane >> 4) * 4;
#pragma unroll
    for (int reg = 0; reg < 4; ++reg) {
        int rg = rbase + reg;
        if (rg < M) {
            float di = AF ? scale[rg] : 1.0f;
#pragma unroll
            for (int j = 0; j < NT; ++j)
                Cb[(size_t)rg * NC + j * 16 + lm] = f2bf(AF ? acc[j][reg] * di : acc[j][reg]);
        }
    }
}

// ---------------- aggregate C=128: half-wave/node, uint2 loads, int4 idx prefetch ----------------
// Epilogue: relu(. + b1) * deg_inv -> bf16 (deg_inv of NEXT layer's row folded here).
__global__ __launch_bounds__(256) void aggregate128_kernel(
    const int2* __restrict__ se, const int* __restrict__ sorted_src,
    const unsigned* __restrict__ val, const float* __restrict__ bias,
    const float* __restrict__ deg_inv, unsigned* __restrict__ outb, int N)
{
    int node = blockIdx.x * 8 + (threadIdx.x >> 5);
    if (node >= N) return;
    int l = threadIdx.x & 31;
    int2 r = se[node];
    int e = r.x;
    const int end = r.y;
    float a0 = 0.f, a1 = 0.f, a2 = 0.f, a3 = 0.f;
    if (e + 4 <= end) {
        int4 idx = *(const int4*)&sorted_src[e];
        for (; e + 8 <= end; e += 4) {
            int4 nidx = *(const int4*)&sorted_src[e + 4];
            uint2 v0 = *(const uint2*)&val[(size_t)idx.x * 64 + 2 * l];
            uint2 v1 = *(const uint2*)&val[(size_t)idx.y * 64 + 2 * l];
            uint2 v2 = *(const uint2*)&val[(size_t)idx.z * 64 + 2 * l];
            uint2 v3 = *(const uint2*)&val[(size_t)idx.w * 64 + 2 * l];
            a0 += (bf2f(v0.x & 0xFFFF) + bf2f(v1.x & 0xFFFF)) + (bf2f(v2.x & 0xFFFF) + bf2f(v3.x & 0xFFFF));
            a1 += (bf2f_hi(v0.x) + bf2f_hi(v1.x)) + (bf2f_hi(v2.x) + bf2f_hi(v3.x));
            a2 += (bf2f(v0.y & 0xFFFF) + bf2f(v1.y & 0xFFFF)) + (bf2f(v2.y & 0xFFFF) + bf2f(v3.y & 0xFFFF));
            a3 += (bf2f_hi(v0.y) + bf2f_hi(v1.y)) + (bf2f_hi(v2.y) + bf2f_hi(v3.y));
            idx = nidx;
        }
        uint2 v0 = *(const uint2*)&val[(size_t)idx.x * 64 + 2 * l];
        uint2 v1 = *(const uint2*)&val[(size_t)idx.y * 64 + 2 * l];
        uint2 v2 = *(const uint2*)&val[(size_t)idx.z * 64 + 2 * l];
        uint2 v3 = *(const uint2*)&val[(size_t)idx.w * 64 + 2 * l];
        a0 += (bf2f(v0.x & 0xFFFF) + bf2f(v1.x & 0xFFFF)) + (bf2f(v2.x & 0xFFFF) + bf2f(v3.x & 0xFFFF));
        a1 += (bf2f_hi(v0.x) + bf2f_hi(v1.x)) + (bf2f_hi(v2.x) + bf2f_hi(v3.x));
        a2 += (bf2f(v0.y & 0xFFFF) + bf2f(v1.y & 0xFFFF)) + (bf2f(v2.y & 0xFFFF) + bf2f(v3.y & 0xFFFF));
        a3 += (bf2f_hi(v0.y) + bf2f_hi(v1.y)) + (bf2f_hi(v2.y) + bf2f_hi(v3.y));
        e += 4;
    }
    for (; e < end; ++e) {
        uint2 v = *(const uint2*)&val[(size_t)sorted_src[e] * 64 + 2 * l];
        a0 += bf2f(v.x & 0xFFFF);
        a1 += bf2f_hi(v.x);
        a2 += bf2f(v.y & 0xFFFF);
        a3 += bf2f_hi(v.y);
    }
    float di = deg_inv[node];
    float4 bv = *(const float4*)&bias[4 * l];
    a0 = fmaxf(a0 + bv.x, 0.f) * di;
    a1 = fmaxf(a1 + bv.y, 0.f) * di;
    a2 = fmaxf(a2 + bv.z, 0.f) * di;
    a3 = fmaxf(a3 + bv.w, 0.f) * di;
    uint2 o;
    o.x = (unsigned)f2bf(a0) | ((unsigned)f2bf(a1) << 16);
    o.y = (unsigned)f2bf(a2) | ((unsigned)f2bf(a3) << 16);
    *(uint2*)&outb[(size_t)node * 64 + 2 * l] = o;
}

// ---------------- aggregate C=64 (bf16 in, fp32 out, +bias): half-wave/node, int4 prefetch ----------------
__global__ __launch_bounds__(256) void aggregate64_kernel(
    const int2* __restrict__ se, const int* __restrict__ sorted_src,
    const unsigned* __restrict__ val, const float* __restrict__ bias,
    float* __restrict__ out, int N)
{
    int node = blockIdx.x * 8 + (threadIdx.x >> 5);
    if (node >= N) return;
    int l = threadIdx.x & 31;
    int2 r = se[node];
    int e = r.x;
    const int end = r.y;
    float ax = 0.f, ay = 0.f;
    if (e + 4 <= end) {
        int4 idx = *(const int4*)&sorted_src[e];
        for (; e + 8 <= end; e += 4) {
            int4 nidx = *(const int4*)&sorted_src[e + 4];
            unsigned v0 = val[(size_t)idx.x * 32 + l];
            unsigned v1 = val[(size_t)idx.y * 32 + l];
            unsigned v2 = val[(size_t)idx.z * 32 + l];
            unsigned v3 = val[(size_t)idx.w * 32 + l];
            ax += (bf2f(v0 & 0xFFFF) + bf2f(v1 & 0xFFFF)) + (bf2f(v2 & 0xFFFF) + bf2f(v3 & 0xFFFF));
            ay += (bf2f_hi(v0) + bf2f_hi(v1)) + (bf2f_hi(v2) + bf2f_hi(v3));
            idx = nidx;
        }
        unsigned v0 = val[(size_t)idx.x * 32 + l];
        unsigned v1 = val[(size_t)idx.y * 32 + l];
        unsigned v2 = val[(size_t)idx.z * 32 + l];
        unsigned v3 = val[(size_t)idx.w * 32 + l];
        ax += (bf2f(v0 & 0xFFFF) + bf2f(v1 & 0xFFFF)) + (bf2f(v2 & 0xFFFF) + bf2f(v3 & 0xFFFF));
        ay += (bf2f_hi(v0) + bf2f_hi(v1)) + (bf2f_hi(v2) + bf2f_hi(v3));
        e += 4;
    }
    for (; e < end; ++e) {
        unsigned v = val[(size_t)sorted_src[e] * 32 + l];
        ax += bf2f(v & 0xFFFF);
        ay += bf2f_hi(v);
    }
    float2 o = make_float2(ax + bias[2 * l], ay + bias[2 * l + 1]);
    *(float2*)&out[(size_t)node * 64 + 2 * l] = o;
}

extern "C" void kernel_launch(void* const* d_in, const int* in_sizes, int n_in,
                              void* d_out, int out_size, void* d_ws, size_t ws_size,
                              hipStream_t stream) {
    const float* x  = (const float*)d_in[0];
    const int*   ei = (const int*)d_in[1];
    const float* W1 = (const float*)d_in[2];
    const float* b1 = (const float*)d_in[3];
    const float* W2 = (const float*)d_in[4];
    const float* b2 = (const float*)d_in[5];
    float* out = (float*)d_out;

    const int N = in_sizes[0] / 128;
    const int E = in_sizes[1] / 2;
    const int* src = ei;
    const int* dst = ei + E;
    const int NB = (N + 255) >> 8;

    char* ws = (char*)d_ws;
    size_t off = 0;
    auto alloc = [&](size_t bytes) {
        void* p = ws + off;
        off = (off + bytes + 255) & ~(size_t)255;
        return p;
    };
    float* deg_inv  = (float*)alloc((size_t)N * 4);
    int2*  se       = (int2*)alloc((size_t)N * 8);
    int*   cnt_d    = (int*)alloc((size_t)NBMAX * 16 * 4 * 2);  // cnt_d | cnt_s adjacent
    int*   cnt_s    = cnt_d + (size_t)NBMAX * 16;
    unsigned short* Wb1 = (unsigned short*)alloc((size_t)128 * 128 * 2);
    unsigned short* Wb2 = (unsigned short*)alloc((size_t)64 * 128 * 2);
    unsigned*      pairs  = (unsigned*)alloc((size_t)NBMAX * CAP * 4);
    unsigned char* srcs_b = (unsigned char*)alloc((size_t)NBMAX * CAP);
    int*   sorted_src = (int*)alloc((size_t)NBMAX * CAP * 4);
    unsigned short* h    = (unsigned short*)alloc((size_t)N * 128 * 2);
    unsigned short* out1 = (unsigned short*)alloc((size_t)N * 128 * 2);
    unsigned short* g    = h;  // h dead after aggregate1

    convw_kernel<<<96, 256, 0, stream>>>(W1, W2, Wb1, Wb2, cnt_d);
    scatter2_kernel<<<(E + 8191) / 8192, 256, 0, stream>>>(src, dst, E, cnt_d, cnt_s,
                                                           pairs, srcs_b, NB);
    bucket_finalize_kernel<<<NB, 256, 0, stream>>>(pairs, srcs_b, cnt_d, cnt_s,
                                                   sorted_src, se, deg_inv, N);

    const int gblocks = (N + 63) / 64;
    // layer 1: h = bf16(di * (x @ W1)); out1 = bf16(relu(Agg(h)+b1) * di)
    gemm_mfma_kernel<128, 1><<<gblocks, 256, 0, stream>>>(x, Wb1, deg_inv, h, N);
    aggregate128_kernel<<<(N + 7) / 8, 256, 0, stream>>>(se, sorted_src, (const unsigned*)h, b1,
                                                         deg_inv, (unsigned*)out1, N);
    // layer 2: g = bf16(out1 @ W2); out = Agg(g) + b2
    gemm_mfma_kernel<64, 0><<<gblocks, 256, 0, stream>>>(out1, Wb2, nullptr, g, N);
    aggregate64_kernel<<<(N + 7) / 8, 256, 0, stream>>>(se, sorted_src, (const unsigned*)g, b2, out, N);
}